// Round 1
// baseline (125.990 us; speedup 1.0000x reference)
//
#include <hip/hip_runtime.h>

// B=32, S=4096, C=64, D=2. x:[B,S,C,D] fp32, W_nonlin/W_coeff:[C,2,2] fp32.
// Per site: y = Wn @ x (2x2), amp = |y|^2, c = amp*y, z = Wc @ c.
// Memory-bound streaming: 64 MiB in + 64 MiB out (134 MB ideal traffic).
//
// This version: the trip count divides exactly (n4 = 4,194,304 float4s,
// 2048 blocks x 256 threads x 8 iters), so we specialize to a fixed 8-deep
// load batch: all 8 global_load_dwordx4 issued before any compute, giving
// 8 outstanding loads/lane (128 B/lane in flight) instead of 1. The old
// grid-stride loop serialized load->waitcnt->compute->store per iteration.
//
// Channel-pair index cp = g & 31 is iteration-invariant because the stride
// (blocks*256) is a multiple of 32, so weights live in 16 registers.

constexpr int THREADS = 256;
constexpr int ITERS   = 8;

__device__ __forceinline__ float4 two_channels(const float4 v,
                                               const float4 wn0, const float4 wn1,
                                               const float4 wc0, const float4 wc1)
{
    float4 r;
    // channel 2cp: input (v.x, v.y)
    {
        float y0  = v.x * wn0.x + v.y * wn0.y;
        float y1  = v.x * wn0.z + v.y * wn0.w;
        float amp = y0 * y0 + y1 * y1;
        float c0  = amp * y0;
        float c1  = amp * y1;
        r.x = c0 * wc0.x + c1 * wc0.y;
        r.y = c0 * wc0.z + c1 * wc0.w;
    }
    // channel 2cp+1: input (v.z, v.w)
    {
        float y0  = v.z * wn1.x + v.w * wn1.y;
        float y1  = v.z * wn1.z + v.w * wn1.w;
        float amp = y0 * y0 + y1 * y1;
        float c0  = amp * y0;
        float c1  = amp * y1;
        r.z = c0 * wc1.x + c1 * wc1.y;
        r.w = c0 * wc1.z + c1 * wc1.w;
    }
    return r;
}

// Specialized: exactly ITERS float4s per thread, no bounds checks.
__global__ __launch_bounds__(THREADS) void fused_cplx_nonlin_unroll(
    const float4* __restrict__ x,
    const float4* __restrict__ Wn,   // [C,2,2] viewed as float4[C]
    const float4* __restrict__ Wc,
    float4* __restrict__ z,
    int stride)                      // gridDim.x * THREADS, multiple of 32
{
    const int g  = blockIdx.x * THREADS + threadIdx.x;
    const int cp = g & 31;

    const float4 wn0 = Wn[2 * cp];
    const float4 wn1 = Wn[2 * cp + 1];
    const float4 wc0 = Wc[2 * cp];
    const float4 wc1 = Wc[2 * cp + 1];

    // Issue all ITERS loads before any use: 8 outstanding vmem ops per lane.
    float4 v[ITERS];
#pragma unroll
    for (int k = 0; k < ITERS; ++k)
        v[k] = x[g + k * stride];

    // Compute + store as each load's data is consumed (compiler staggers
    // s_waitcnt vmcnt(7..0)); v[k] registers retire as we go.
#pragma unroll
    for (int k = 0; k < ITERS; ++k)
        z[g + k * stride] = two_channels(v[k], wn0, wn1, wc0, wc1);
}

// Generic fallback (original grid-stride form) for shapes that don't divide.
__global__ __launch_bounds__(THREADS) void fused_cplx_nonlin_generic(
    const float4* __restrict__ x,
    const float4* __restrict__ Wn,
    const float4* __restrict__ Wc,
    float4* __restrict__ z,
    int n4, int stride)
{
    const int g  = blockIdx.x * THREADS + threadIdx.x;
    const int cp = g & 31;

    const float4 wn0 = Wn[2 * cp];
    const float4 wn1 = Wn[2 * cp + 1];
    const float4 wc0 = Wc[2 * cp];
    const float4 wc1 = Wc[2 * cp + 1];

    for (int idx = g; idx < n4; idx += stride)
        z[idx] = two_channels(x[idx], wn0, wn1, wc0, wc1);
}

extern "C" void kernel_launch(void* const* d_in, const int* in_sizes, int n_in,
                              void* d_out, int out_size, void* d_ws, size_t ws_size,
                              hipStream_t stream) {
    const float4* x  = (const float4*)d_in[0];
    const float4* Wn = (const float4*)d_in[1];
    const float4* Wc = (const float4*)d_in[2];
    float4* z        = (float4*)d_out;

    const int n4 = in_sizes[0] / 4;              // 4,194,304 float4s

    if (n4 % (THREADS * ITERS) == 0) {
        // 4,194,304 / 2048 = 2048 blocks -> 8 blocks/CU, 32 waves/CU.
        const int blocks = n4 / (THREADS * ITERS);
        const int stride = blocks * THREADS;     // 524,288: multiple of 32
        fused_cplx_nonlin_unroll<<<blocks, THREADS, 0, stream>>>(
            x, Wn, Wc, z, stride);
    } else {
        const int blocks = 2048;
        const int stride = blocks * THREADS;
        fused_cplx_nonlin_generic<<<blocks, THREADS, 0, stream>>>(
            x, Wn, Wc, z, n4, stride);
    }
}

// Round 2
// 112.993 us; speedup vs baseline: 1.1150x; 1.1150x over previous
//
#include <hip/hip_runtime.h>

// B=32, S=4096, C=64, D=2. x:[B,S,C,D] fp32, W_nonlin/W_coeff:[C,2,2] fp32.
// Per site: y = Wn @ x (2x2), amp = |y|^2, c = amp*y, z = Wc @ c.
// Memory-bound streaming: 64 MiB in + 64 MiB out (134 MB ideal traffic).
//
// Round-1 lesson: batch-8 loads at 8-MiB stride ran at 2.9 TB/s (44 us) --
// WORSE than the naive grid-stride loop (3.9 TB/s). Theory: 8 concurrent
// loads per lane at 8-MiB stride map to the same HBM channel/bank, different
// rows -> machine-wide row-buffer thrash.
//
// This version keeps MLP=8 but makes each block's footprint CONTIGUOUS:
// block b owns float4s [b*2048, (b+1)*2048) (32 KiB read + 32 KiB written),
// thread t touches idx = b*2048 + k*256 + t. A lane's 8 in-flight loads span
// 32 KiB instead of 64 MiB; wave-instantaneous footprint is dense and
// DRAM-row-friendly. Coalescing unchanged (64 lanes x 16 B contiguous).
//
// Channel-pair invariance: idx & 31 == t & 31 (2048 and 256 are both
// multiples of 32), so weights stay in 16 registers, loaded once.

constexpr int THREADS = 256;
constexpr int ITERS   = 8;
constexpr int CHUNK   = THREADS * ITERS;   // 2048 float4 = 32 KiB per block

__device__ __forceinline__ float4 two_channels(const float4 v,
                                               const float4 wn0, const float4 wn1,
                                               const float4 wc0, const float4 wc1)
{
    float4 r;
    // channel 2cp: input (v.x, v.y)
    {
        float y0  = v.x * wn0.x + v.y * wn0.y;
        float y1  = v.x * wn0.z + v.y * wn0.w;
        float amp = y0 * y0 + y1 * y1;
        float c0  = amp * y0;
        float c1  = amp * y1;
        r.x = c0 * wc0.x + c1 * wc0.y;
        r.y = c0 * wc0.z + c1 * wc0.w;
    }
    // channel 2cp+1: input (v.z, v.w)
    {
        float y0  = v.z * wn1.x + v.w * wn1.y;
        float y1  = v.z * wn1.z + v.w * wn1.w;
        float amp = y0 * y0 + y1 * y1;
        float c0  = amp * y0;
        float c1  = amp * y1;
        r.z = c0 * wc1.x + c1 * wc1.y;
        r.w = c0 * wc1.z + c1 * wc1.w;
    }
    return r;
}

// Specialized: block-contiguous chunks, exactly ITERS float4s per thread.
__global__ __launch_bounds__(THREADS) void fused_cplx_nonlin_chunk(
    const float4* __restrict__ x,
    const float4* __restrict__ Wn,   // [C,2,2] viewed as float4[C]
    const float4* __restrict__ Wc,
    float4* __restrict__ z)
{
    const int t    = threadIdx.x;
    const int base = blockIdx.x * CHUNK + t;
    const int cp   = t & 31;

    const float4 wn0 = Wn[2 * cp];
    const float4 wn1 = Wn[2 * cp + 1];
    const float4 wc0 = Wc[2 * cp];
    const float4 wc1 = Wc[2 * cp + 1];

    // 8 outstanding loads per lane, all within this block's 32-KiB chunk.
    float4 v[ITERS];
#pragma unroll
    for (int k = 0; k < ITERS; ++k)
        v[k] = x[base + k * THREADS];

#pragma unroll
    for (int k = 0; k < ITERS; ++k)
        z[base + k * THREADS] = two_channels(v[k], wn0, wn1, wc0, wc1);
}

// Generic fallback (grid-stride) for shapes that don't divide.
__global__ __launch_bounds__(THREADS) void fused_cplx_nonlin_generic(
    const float4* __restrict__ x,
    const float4* __restrict__ Wn,
    const float4* __restrict__ Wc,
    float4* __restrict__ z,
    int n4, int stride)
{
    const int g  = blockIdx.x * THREADS + threadIdx.x;
    const int cp = g & 31;

    const float4 wn0 = Wn[2 * cp];
    const float4 wn1 = Wn[2 * cp + 1];
    const float4 wc0 = Wc[2 * cp];
    const float4 wc1 = Wc[2 * cp + 1];

    for (int idx = g; idx < n4; idx += stride)
        z[idx] = two_channels(x[idx], wn0, wn1, wc0, wc1);
}

extern "C" void kernel_launch(void* const* d_in, const int* in_sizes, int n_in,
                              void* d_out, int out_size, void* d_ws, size_t ws_size,
                              hipStream_t stream) {
    const float4* x  = (const float4*)d_in[0];
    const float4* Wn = (const float4*)d_in[1];
    const float4* Wc = (const float4*)d_in[2];
    float4* z        = (float4*)d_out;

    const int n4 = in_sizes[0] / 4;              // 4,194,304 float4s

    if (n4 % CHUNK == 0) {
        // 4,194,304 / 2048 = 2048 blocks -> 8 blocks/CU, 32 waves/CU.
        const int blocks = n4 / CHUNK;
        fused_cplx_nonlin_chunk<<<blocks, THREADS, 0, stream>>>(x, Wn, Wc, z);
    } else {
        const int blocks = 2048;
        const int stride = blocks * THREADS;
        fused_cplx_nonlin_generic<<<blocks, THREADS, 0, stream>>>(
            x, Wn, Wc, z, n4, stride);
    }
}